// Round 10
// baseline (354.180 us; speedup 1.0000x reference)
//
#include <hip/hip_runtime.h>
#include <hip/hip_bf16.h>
#include <cmath>
#include <cstdint>
#include <cstddef>

#define B_  2
#define S_  2048
#define D_  1024
#define H_  16
#define DK_ 64
#define NEG_BIG (-1e30f)
// 0.125 * log2(e): folded into Q projection; softmax runs in exp2 domain.
#define QSCALE 0.1803368801111204f

typedef __attribute__((ext_vector_type(8))) short bf16x8;
typedef __attribute__((ext_vector_type(4))) float f32x4;
typedef __attribute__((ext_vector_type(16))) float f32x16;

static __device__ __forceinline__ unsigned short f2bf(float f) {
  __hip_bfloat16 h = __float2bfloat16(f);
  return *reinterpret_cast<unsigned short*>(&h);
}

static __device__ __forceinline__ unsigned cvtpk(float lo, float hi) {
  unsigned d;
  asm("v_cvt_pk_bf16_f32 %0, %1, %2" : "=v"(d) : "v"(lo), "v"(hi));
  return d;
}
// native 2^x: 1 instruction, flushes tiny results to 0 (wanted for -1e30 masks)
static __device__ __forceinline__ float vexp2(float x) {
  float r;
  asm("v_exp_f32 %0, %1" : "=v"(r) : "v"(x));
  return r;
}
#define SWAP32(a, b) asm("v_permlane32_swap_b32 %0, %1" : "+v"(a), "+v"(b))

typedef __attribute__((address_space(3))) unsigned int lds_u32;
typedef __attribute__((address_space(1))) const unsigned int glb_u32;

// ---------------------------------------------------------------------------
// pack mask via ballot: 1 coalesced int per lane; wave -> 2 bitmask words.
// ---------------------------------------------------------------------------
__global__ void pack_mask_kernel(const int* __restrict__ mask,
                                 unsigned* __restrict__ bits) {
  const int t = blockIdx.x * 256 + threadIdx.x;
  const unsigned long long ball = __ballot(mask[t] != 0);
  const int lane = threadIdx.x & 63;
  if ((lane & 31) == 0)
    bits[t >> 5] = (lane == 0) ? (unsigned)ball : (unsigned)(ball >> 32);
}

// ---------------------------------------------------------------------------
// W [K=1024][N=1024] fp32 -> Wt bf16 [N][K], fused over 4 weights (blockIdx.z)
// ---------------------------------------------------------------------------
__global__ __launch_bounds__(256) void transpose_w_kernel(
    const float* __restrict__ w0, const float* __restrict__ w1,
    const float* __restrict__ w2, const float* __restrict__ w3,
    unsigned short* __restrict__ t0, unsigned short* __restrict__ t1,
    unsigned short* __restrict__ t2, unsigned short* __restrict__ t3) {
  __shared__ unsigned short tile[32][33];
  const int z = blockIdx.z;
  const float* W = (z == 0) ? w0 : (z == 1) ? w1 : (z == 2) ? w2 : w3;
  unsigned short* Wt = (z == 0) ? t0 : (z == 1) ? t1 : (z == 2) ? t2 : t3;
  const int r0 = blockIdx.y * 32, c0 = blockIdx.x * 32;
  const int t = threadIdx.x;
  {
    const int r = t >> 3, c4 = (t & 7) * 4;
    float4 v = *reinterpret_cast<const float4*>(&W[(size_t)(r0 + r) * D_ + c0 + c4]);
    tile[c4 + 0][r] = f2bf(v.x);
    tile[c4 + 1][r] = f2bf(v.y);
    tile[c4 + 2][r] = f2bf(v.z);
    tile[c4 + 3][r] = f2bf(v.w);
  }
  __syncthreads();
  {
    const int n = t >> 3, k4 = (t & 7) * 4;
    ushort4 o = {tile[n][k4 + 0], tile[n][k4 + 1], tile[n][k4 + 2], tile[n][k4 + 3]};
    *reinterpret_cast<ushort4*>(&Wt[(size_t)(c0 + n) * D_ + r0 + k4]) = o;
  }
}

// ---------------------------------------------------------------------------
// Fused QKV projection, 128x128 tile, BK=32: A is fp32 (converted in-kernel
// during staging: float4 loads issued pre-barrier, cvt_pk, ds_write_b128);
// Wt staged via global_load_lds. z selects {q,k,v}.
// ---------------------------------------------------------------------------
__global__ __launch_bounds__(256) void qkv_gemm_kernel(
    const float* __restrict__ qa, const float* __restrict__ ka,
    const float* __restrict__ va, const unsigned short* __restrict__ wtq,
    const unsigned short* __restrict__ wtk, const unsigned short* __restrict__ wtv,
    const float* __restrict__ bq, const float* __restrict__ bk,
    const float* __restrict__ bv, unsigned short* __restrict__ Qh,
    unsigned short* __restrict__ Kh, unsigned short* __restrict__ VT) {
  constexpr int K = D_;
  __shared__ __attribute__((aligned(16))) unsigned short as_[128 * 32];
  __shared__ __attribute__((aligned(16))) unsigned short bs_[128 * 32];
  const int z = blockIdx.z;
  const float* A = (z == 0) ? qa : (z == 1) ? ka : va;
  const unsigned short* Wt = (z == 0) ? wtq : (z == 1) ? wtk : wtv;
  const float* bias = (z == 0) ? bq : (z == 1) ? bk : bv;

  const int bm = blockIdx.x * 128, bn = blockIdx.y * 128;
  const int t = threadIdx.x, wv = t >> 6, lane = t & 63;
  const int r = lane & 15, g = lane >> 4;
  const int wr = (wv >> 1) * 64, wc = (wv & 1) * 64;
  const int srow = 16 * wv + (lane >> 2);  // B staging row within 64-row chunk
  const int scol = (lane & 3) * 8;
  // A staging: slot s (and s+256): row=s>>2, k-quad=(s&3)*8
  const int ar0 = t >> 2, ak0 = (t & 3) * 8;
  const int ar1 = (t + 256) >> 2, ak1 = ak0;

  f32x4 acc[4][4] = {};

  for (int k0 = 0; k0 < K; k0 += 32) {
    // issue A fp32 loads before the barrier (overlap previous compute)
    const float4* ap0 = reinterpret_cast<const float4*>(&A[(size_t)(bm + ar0) * K + k0 + ak0]);
    const float4* ap1 = reinterpret_cast<const float4*>(&A[(size_t)(bm + ar1) * K + k0 + ak1]);
    float4 a0 = ap0[0], a1 = ap0[1];
    float4 a2 = ap1[0], a3 = ap1[1];
    __syncthreads();  // previous iteration's LDS readers done
    __builtin_amdgcn_global_load_lds(
        (glb_u32*)&Wt[(size_t)(bn + srow) * K + k0 + scol],
        (lds_u32*)(bs_ + wv * 512), 16, 0, 0);
    __builtin_amdgcn_global_load_lds(
        (glb_u32*)&Wt[(size_t)(bn + 64 + srow) * K + k0 + scol],
        (lds_u32*)(bs_ + wv * 512 + 2048), 16, 0, 0);
    union { unsigned u[4]; bf16x8 v; } w0, w1;
    w0.u[0] = cvtpk(a0.x, a0.y); w0.u[1] = cvtpk(a0.z, a0.w);
    w0.u[2] = cvtpk(a1.x, a1.y); w0.u[3] = cvtpk(a1.z, a1.w);
    w1.u[0] = cvtpk(a2.x, a2.y); w1.u[1] = cvtpk(a2.z, a2.w);
    w1.u[2] = cvtpk(a3.x, a3.y); w1.u[3] = cvtpk(a3.z, a3.w);
    *reinterpret_cast<bf16x8*>(&as_[(size_t)t * 8]) = w0.v;
    *reinterpret_cast<bf16x8*>(&as_[(size_t)(t + 256) * 8]) = w1.v;
    __syncthreads();  // A writes + B gload visible

    bf16x8 a[4], bfr[4];
#pragma unroll
    for (int mf = 0; mf < 4; ++mf)
      a[mf] = *reinterpret_cast<const bf16x8*>(&as_[(wr + 16 * mf + r) * 32 + 8 * g]);
#pragma unroll
    for (int nf = 0; nf < 4; ++nf)
      bfr[nf] = *reinterpret_cast<const bf16x8*>(&bs_[(wc + 16 * nf + r) * 32 + 8 * g]);
#pragma unroll
    for (int mf = 0; mf < 4; ++mf)
#pragma unroll
      for (int nf = 0; nf < 4; ++nf)
        acc[mf][nf] = __builtin_amdgcn_mfma_f32_16x16x32_bf16(a[mf], bfr[nf],
                                                              acc[mf][nf], 0, 0, 0);
  }

#pragma unroll
  for (int mf = 0; mf < 4; ++mf)
#pragma unroll
    for (int nf = 0; nf < 4; ++nf)
#pragma unroll
      for (int reg = 0; reg < 4; ++reg) {
        const int row = bm + wr + 16 * mf + 4 * g + reg;
        const int col = bn + wc + 16 * nf + r;
        const float v = acc[mf][nf][reg] + bias[col];
        const int bb = row >> 11, s = row & (S_ - 1);
        const int h = col >> 6, dk = col & (DK_ - 1);
        if (z == 0)
          Qh[(((size_t)(bb * H_ + h)) * S_ + s) * DK_ + dk] = f2bf(v * QSCALE);
        else if (z == 1)
          Kh[(((size_t)(bb * H_ + h)) * S_ + s) * DK_ + dk] = f2bf(v);
        else
          VT[(((size_t)(bb * H_ + h)) * DK_ + dk) * S_ + s] = f2bf(v);
      }
}

// ---------------------------------------------------------------------------
// Output projection, 128x128 tile: ctx bf16 [B,S,D] @ Wo^T + bo -> fp32 out.
// ---------------------------------------------------------------------------
__global__ __launch_bounds__(256) void out_gemm_kernel(
    const unsigned short* __restrict__ A, const unsigned short* __restrict__ Wt,
    const float* __restrict__ bias, float* __restrict__ Cout) {
  constexpr int K = D_;
  __shared__ __attribute__((aligned(16))) unsigned short as_[128 * 32];
  __shared__ __attribute__((aligned(16))) unsigned short bs_[128 * 32];
  const int bm = blockIdx.x * 128, bn = blockIdx.y * 128;
  const int t = threadIdx.x, wv = t >> 6, lane = t & 63;
  const int r = lane & 15, g = lane >> 4;
  const int wr = (wv >> 1) * 64, wc = (wv & 1) * 64;
  const int srow = 16 * wv + (lane >> 2);
  const int scol = (lane & 3) * 8;

  f32x4 acc[4][4] = {};

  for (int k0 = 0; k0 < K; k0 += 32) {
    __syncthreads();
    __builtin_amdgcn_global_load_lds(
        (glb_u32*)&A[(size_t)(bm + srow) * K + k0 + scol],
        (lds_u32*)(as_ + wv * 512), 16, 0, 0);
    __builtin_amdgcn_global_load_lds(
        (glb_u32*)&A[(size_t)(bm + 64 + srow) * K + k0 + scol],
        (lds_u32*)(as_ + wv * 512 + 2048), 16, 0, 0);
    __builtin_amdgcn_global_load_lds(
        (glb_u32*)&Wt[(size_t)(bn + srow) * K + k0 + scol],
        (lds_u32*)(bs_ + wv * 512), 16, 0, 0);
    __builtin_amdgcn_global_load_lds(
        (glb_u32*)&Wt[(size_t)(bn + 64 + srow) * K + k0 + scol],
        (lds_u32*)(bs_ + wv * 512 + 2048), 16, 0, 0);
    __syncthreads();

    bf16x8 a[4], bfr[4];
#pragma unroll
    for (int mf = 0; mf < 4; ++mf)
      a[mf] = *reinterpret_cast<const bf16x8*>(&as_[(wr + 16 * mf + r) * 32 + 8 * g]);
#pragma unroll
    for (int nf = 0; nf < 4; ++nf)
      bfr[nf] = *reinterpret_cast<const bf16x8*>(&bs_[(wc + 16 * nf + r) * 32 + 8 * g]);
#pragma unroll
    for (int mf = 0; mf < 4; ++mf)
#pragma unroll
      for (int nf = 0; nf < 4; ++nf)
        acc[mf][nf] = __builtin_amdgcn_mfma_f32_16x16x32_bf16(a[mf], bfr[nf],
                                                              acc[mf][nf], 0, 0, 0);
  }

#pragma unroll
  for (int mf = 0; mf < 4; ++mf)
#pragma unroll
    for (int nf = 0; nf < 4; ++nf)
#pragma unroll
      for (int reg = 0; reg < 4; ++reg) {
        const int row = bm + wr + 16 * mf + 4 * g + reg;
        const int col = bn + wc + 16 * nf + r;
        Cout[(size_t)row * D_ + col] = acc[mf][nf][reg] + bias[col];
      }
}

// ---------------------------------------------------------------------------
// MFMA flash attention: 64-key iterations (2 score vectors share one
// max/rescale/sum), asm v_exp_f32, swapped-QK^T 32x32x16, split-K(4),
// defer-max, T12 pack. K reloaded post-QK^T (covered by softmax+PV);
// V + mask loaded at iteration top.
// ---------------------------------------------------------------------------
__global__ __launch_bounds__(256) void attn_mfma_kernel(
    const unsigned short* __restrict__ Qh, const unsigned short* __restrict__ Kh,
    const unsigned short* __restrict__ VT, const unsigned* __restrict__ mbits,
    unsigned short* __restrict__ ctx) {
  __shared__ float mlds[4][32];
  __shared__ float llds[4][32];
  __shared__ float olds[3][2][16][64];

  const int flat = blockIdx.x;
  const int bh = (flat & 7) * 4 + ((flat >> 3) & 3);  // 4 heads per XCD
  const int qblk = flat >> 5;                          // 0..63
  const int b = bh >> 4, h = bh & 15;
  const int kh = threadIdx.x >> 6, lane = threadIdx.x & 63;
  const int ql = lane & 31, hi = lane >> 5;
  const int qrow = qblk * 32 + ql;

  const unsigned short* Qrow = &Qh[((size_t)bh * S_ + qrow) * DK_];
  bf16x8 qf[4];
#pragma unroll
  for (int i = 0; i < 4; ++i)
    qf[i] = *(const bf16x8*)&Qrow[16 * i + 8 * hi];

  const unsigned short* Khead = &Kh[(size_t)bh * S_ * DK_];
  const unsigned short* Vhead = &VT[(size_t)bh * DK_ * S_];

  f32x16 o0 = {}, o1 = {};
  float m = NEG_BIG, l = 0.f;

  // wave kh covers keys [kh*512, kh*512+512) as 8 iterations of 64 keys
  const unsigned short* kbase = Khead + ((size_t)(kh * 512 + ql)) * DK_ + 8 * hi;
  const unsigned short* vb0 = Vhead + (size_t)ql * S_ + kh * 512 + 8 * hi;
  const unsigned short* vb1 = vb0 + (size_t)32 * S_;
  const unsigned* mp = &mbits[((size_t)b * S_ + qrow) * (S_ / 32) + kh * 16];

  bf16x8 kc0[4], kc1[4];
#pragma unroll
  for (int i = 0; i < 4; ++i) {
    kc0[i] = *(const bf16x8*)(kbase + 16 * i);
    kc1[i] = *(const bf16x8*)(kbase + 2048 + 16 * i);
  }
  kbase += 4096;

#pragma unroll 1
  for (int it = 0; it < 8; ++it) {
    // ---- V + mask for this 64-key tile (consumed at iteration end) ----
    const uint2 mw = *reinterpret_cast<const uint2*>(mp);
    mp += 2;
    bf16x8 vf0[4], vf1[4];
#pragma unroll
    for (int kk = 0; kk < 4; ++kk) {
      vf0[kk] = *(const bf16x8*)(vb0 + kk * 16);
      vf1[kk] = *(const bf16x8*)(vb1 + kk * 16);
    }
    vb0 += 64;
    vb1 += 64;

    // ---- QK^T for both 32-key halves ----
    f32x16 sc0 = {}, sc1 = {};
#pragma unroll
    for (int i = 0; i < 4; ++i)
      sc0 = __builtin_amdgcn_mfma_f32_32x32x16_bf16(kc0[i], qf[i], sc0, 0, 0, 0);
#pragma unroll
    for (int i = 0; i < 4; ++i)
      sc1 = __builtin_amdgcn_mfma_f32_32x32x16_bf16(kc1[i], qf[i], sc1, 0, 0, 0);

    // ---- reload K for next iteration (latency covered by softmax+PV) ----
    if (it < 7) {
#pragma unroll
      for (int i = 0; i < 4; ++i) {
        kc0[i] = *(const bf16x8*)(kbase + 16 * i);
        kc1[i] = *(const bf16x8*)(kbase + 2048 + 16 * i);
      }
      kbase += 4096;
    }

    // ---- mask ----
    const unsigned m0 = mw.x >> (4 * hi), m1 = mw.y >> (4 * hi);
#pragma unroll
    for (int reg = 0; reg < 16; ++reg) {
      const int creg = (reg & 3) + 8 * (reg >> 2);
      if ((m0 >> creg) & 1u) sc0[reg] = NEG_BIG;
      if ((m1 >> creg) & 1u) sc1[reg] = NEG_BIG;
    }

    // ---- joint max over 64 keys (fmax triples -> v_max3) ----
    float px;
    {
      float t0 = fmaxf(fmaxf(sc0[0], sc0[1]), sc0[2]);
      float t1 = fmaxf(fmaxf(sc0[3], sc0[4]), sc0[5]);
      float t2 = fmaxf(fmaxf(sc0[6], sc0[7]), sc0[8]);
      float t3 = fmaxf(fmaxf(sc0[9], sc0[10]), sc0[11]);
      float t4 = fmaxf(fmaxf(sc0[12], sc0[13]), sc0[14]);
      float t5 = fmaxf(fmaxf(sc0[15], sc1[0]), sc1[1]);
      float t6 = fmaxf(fmaxf(sc1[2], sc1[3]), sc1[4]);
      float t7 = fmaxf(fmaxf(sc1[5], sc1[6]), sc1[7]);
      float t8 = fmaxf(fmaxf(sc1[8], sc1[9]), sc1[10]);
      float t9 = fmaxf(fmaxf(sc1[11], sc1[12]), sc1[13]);
      float ta = fmaxf(sc1[14], sc1[15]);
      float u0 = fmaxf(fmaxf(t0, t1), t2);
      float u1 = fmaxf(fmaxf(t3, t4), t5);
      float u2 = fmaxf(fmaxf(t6, t7), t8);
      float u3 = fmaxf(t9, ta);
      px = fmaxf(fmaxf(u0, u1), fmaxf(u2, u3));
    }
    px = fmaxf(px, __shfl_xor(px, 32));

    // ---- defer-max rescale (THR=11 in log2 domain) ----
    if (!__all(px - m <= 11.f)) {
      const float mn = fmaxf(m, px);
      const float al = vexp2(m - mn);
      m = mn;
      l *= al;
#pragma unroll
      for (int reg = 0; reg < 16; ++reg) { o0[reg] *= al; o1[reg] *= al; }
    }

    // ---- p = 2^(s-m), joint sum ----
#pragma unroll
    for (int reg = 0; reg < 16; ++reg) {
      sc0[reg] = vexp2(sc0[reg] - m);
      sc1[reg] = vexp2(sc1[reg] - m);
    }
    {
      float s0 = (sc0[0] + sc0[1]) + (sc0[2] + sc0[3]);
      float s1 = (sc0[4] + sc0[5]) + (sc0[6] + sc0[7]);
      float s2 = (sc0[8] + sc0[9]) + (sc0[10] + sc0[11]);
      float s3 = (sc0[12] + sc0[13]) + (sc0[14] + sc0[15]);
      float s4 = (sc1[0] + sc1[1]) + (sc1[2] + sc1[3]);
      float s5 = (sc1[4] + sc1[5]) + (sc1[6] + sc1[7]);
      float s6 = (sc1[8] + sc1[9]) + (sc1[10] + sc1[11]);
      float s7 = (sc1[12] + sc1[13]) + (sc1[14] + sc1[15]);
      float rs = ((s0 + s1) + (s2 + s3)) + ((s4 + s5) + (s6 + s7));
      rs += __shfl_xor(rs, 32);
      l += rs;
    }

    // ---- pack both halves (T12) ----
    unsigned w0 = cvtpk(sc0[0], sc0[1]), w2p = cvtpk(sc0[4], sc0[5]);
    unsigned w1 = cvtpk(sc0[2], sc0[3]), w3p = cvtpk(sc0[6], sc0[7]);
    unsigned x0 = cvtpk(sc0[8], sc0[9]), x2p = cvtpk(sc0[12], sc0[13]);
    unsigned x1 = cvtpk(sc0[10], sc0[11]), x3p = cvtpk(sc0[14], sc0[15]);
    unsigned y0 = cvtpk(sc1[0], sc1[1]), y2p = cvtpk(sc1[4], sc1[5]);
    unsigned y1 = cvtpk(sc1[2], sc1[3]), y3p = cvtpk(sc1[6], sc1[7]);
    unsigned z0 = cvtpk(sc1[8], sc1[9]), z2p = cvtpk(sc1[12], sc1[13]);
    unsigned z1 = cvtpk(sc1[10], sc1[11]), z3p = cvtpk(sc1[14], sc1[15]);
    SWAP32(w0, w2p); SWAP32(w1, w3p); SWAP32(x0, x2p); SWAP32(x1, x3p);
    SWAP32(y0, y2p); SWAP32(y1, y3p); SWAP32(z0, z2p); SWAP32(z1, z3p);
    union { unsigned u[4]; bf16x8 v; } pu0, pu1, pu2, pu3;
    pu0.u[0] = w0; pu0.u[1] = w1; pu0.u[2] = w2p; pu0.u[3] = w3p;
    pu1.u[0] = x0; pu1.u[1] = x1; pu1.u[2] = x2p; pu1.u[3] = x3p;
    pu2.u[0] = y0; pu2.u[1] = y1; pu2.u[2] = y2p; pu2.u[3] = y3p;
    pu3.u[0] = z0; pu3.u[1] = z1; pu3.u[2] = z2p; pu3.u[3] = z3p;

    // ---- PV over 64 keys ----
    o0 = __builtin_amdgcn_mfma_f32_32x32x16_bf16(pu0.v, vf0[0], o0, 0, 0, 0);
    o0 = __builtin_amdgcn_mfma_f32_32x32x16_bf16(pu1.v, vf0[1], o0, 0, 0, 0);
    o0 = __builtin_amdgcn_mfma_f32_32x32x16_bf16(pu2.v, vf0[2], o0, 0, 0, 0);
    o0 = __builtin_amdgcn_mfma_f32_32x32x16_bf16(pu3.v, vf0[3], o0, 0, 0, 0);
    o1 = __builtin_amdgcn_mfma_f32_32x32x16_bf16(pu0.v, vf1[0], o1, 0, 0, 0);
    o1 = __builtin_amdgcn_mfma_f32_32x32x16_bf16(pu1.v, vf1[1], o1, 0, 0, 0);
    o1 = __builtin_amdgcn_mfma_f32_32x32x16_bf16(pu2.v, vf1[2], o1, 0, 0, 0);
    o1 = __builtin_amdgcn_mfma_f32_32x32x16_bf16(pu3.v, vf1[3], o1, 0, 0, 0);
  }

  // ---- 4-way split-K merge ----
  if (lane < 32) {
    mlds[kh][ql] = m;
    llds[kh][ql] = l;
  }
  if (kh < 3) {
#pragma unroll
    for (int reg = 0; reg < 16; ++reg) {
      olds[kh][0][reg][lane] = o0[reg];
      olds[kh][1][reg][lane] = o1[reg];
    }
  }
  __syncthreads();
  if (kh == 3) {
#pragma unroll
    for (int reg = 0; reg < 16; ++reg) {
      const int crow = (reg & 3) + 8 * (reg >> 2) + 4 * hi;
      const float m0 = mlds[0][crow], m1 = mlds[1][crow];
      const float m2 = mlds[2][crow], m3 = mlds[3][crow];
      const float ms = fmaxf(fmaxf(m0, m1), fmaxf(m2, m3));
      const float f0 = vexp2(m0 - ms), f1 = vexp2(m1 - ms);
      const float f2 = vexp2(m2 - ms), f3 = vexp2(m3 - ms);
      const float ls = llds[0][crow] * f0 + llds[1][crow] * f1 +
                       llds[2][crow] * f2 + llds[3][crow] * f3;
      const float inv = (ms == NEG_BIG) ? 0.f : 1.f / ls;  // fully-masked -> 0
      const float v0 = (olds[0][0][reg][lane] * f0 + olds[1][0][reg][lane] * f1 +
                        olds[2][0][reg][lane] * f2 + o0[reg] * f3) * inv;
      const float v1 = (olds[0][1][reg][lane] * f0 + olds[1][1][reg][lane] * f1 +
                        olds[2][1][reg][lane] * f2 + o1[reg] * f3) * inv;
      const int q = qblk * 32 + crow;
      unsigned short* cp = &ctx[((size_t)(b * S_ + q)) * D_ + h * DK_];
      cp[ql] = f2bf(v0);
      cp[32 + ql] = f2bf(v1);
    }
  }
}

// ---------------------------------------------------------------------------
// Launch
// ---------------------------------------------------------------------------
extern "C" void kernel_launch(void* const* d_in, const int* in_sizes, int n_in,
                              void* d_out, int out_size, void* d_ws,
                              size_t ws_size, hipStream_t stream) {
  const float* query = (const float*)d_in[0];
  const float* key   = (const float*)d_in[1];
  const float* value = (const float*)d_in[2];
  const int*   mask  = (const int*)d_in[3];
  const float* Wq = (const float*)d_in[4];
  const float* bq = (const float*)d_in[5];
  const float* Wk = (const float*)d_in[6];
  const float* bk = (const float*)d_in[7];
  const float* Wv = (const float*)d_in[8];
  const float* bv = (const float*)d_in[9];
  const float* Wo = (const float*)d_in[10];
  const float* bo = (const float*)d_in[11];
  float* out = (float*)d_out;

  const size_t nElem = (size_t)B_ * S_ * D_;  // 4,194,304
  const size_t wElem = (size_t)D_ * D_;       // 1,048,576
  unsigned short* ws = (unsigned short*)d_ws;
  unsigned short* wtq  = ws;
  unsigned short* wtk  = wtq + wElem;
  unsigned short* wtv  = wtk + wElem;
  unsigned short* wto  = wtv + wElem;
  unsigned short* Qh   = wto + wElem;
  unsigned short* Kh   = Qh + nElem;
  unsigned short* VT   = Kh + nElem;
  unsigned short* ctxb = VT + nElem;
  unsigned* mbits = (unsigned*)(ctxb + nElem);

  // 1) pack mask (ballot)
  pack_mask_kernel<<<(B_ * S_ * S_) / 256, 256, 0, stream>>>(mask, mbits);
  // 2) transpose+convert weights (fused x4)
  {
    dim3 grid(32, 32, 4);
    transpose_w_kernel<<<grid, 256, 0, stream>>>(Wq, Wk, Wv, Wo, wtq, wtk, wtv, wto);
  }
  // 3) QKV projections (fp32 A staged+converted in-kernel)
  {
    dim3 grid(32, 8, 3);
    qkv_gemm_kernel<<<grid, 256, 0, stream>>>(query, key, value, wtq, wtk, wtv,
                                              bq, bk, bv, Qh, Kh, VT);
  }
  // 4) attention (split-K x4, 64-key iterations)
  attn_mfma_kernel<<<2048, 256, 0, stream>>>(Qh, Kh, VT, mbits, ctxb);
  // 5) output projection
  {
    dim3 grid(32, 8);
    out_gemm_kernel<<<grid, 256, 0, stream>>>(ctxb, wto, bo, out);
  }
}

// Round 11
// 309.627 us; speedup vs baseline: 1.1439x; 1.1439x over previous
//
#include <hip/hip_runtime.h>
#include <hip/hip_bf16.h>
#include <cmath>
#include <cstdint>
#include <cstddef>

#define B_  2
#define S_  2048
#define D_  1024
#define H_  16
#define DK_ 64
#define NEG_BIG (-1e30f)
// 0.125 * log2(e): folded into Q projection; softmax runs in exp2 domain.
#define QSCALE 0.1803368801111204f

typedef __attribute__((ext_vector_type(8))) short bf16x8;
typedef __attribute__((ext_vector_type(4))) float f32x4;
typedef __attribute__((ext_vector_type(16))) float f32x16;

static __device__ __forceinline__ unsigned short f2bf(float f) {
  __hip_bfloat16 h = __float2bfloat16(f);
  return *reinterpret_cast<unsigned short*>(&h);
}

static __device__ __forceinline__ unsigned cvtpk(float lo, float hi) {
  unsigned d;
  asm("v_cvt_pk_bf16_f32 %0, %1, %2" : "=v"(d) : "v"(lo), "v"(hi));
  return d;
}
// native 2^x: 1 instruction, flushes tiny results to 0 (wanted for -1e30 masks)
static __device__ __forceinline__ float vexp2(float x) {
  float r;
  asm("v_exp_f32 %0, %1" : "=v"(r) : "v"(x));
  return r;
}
#define SWAP32(a, b) asm("v_permlane32_swap_b32 %0, %1" : "+v"(a), "+v"(b))

typedef __attribute__((address_space(3))) unsigned int lds_u32;
typedef __attribute__((address_space(1))) const unsigned int glb_u32;

// ---------------------------------------------------------------------------
// pack mask via ballot: 1 coalesced int per lane; wave -> 2 bitmask words.
// ---------------------------------------------------------------------------
__global__ void pack_mask_kernel(const int* __restrict__ mask,
                                 unsigned* __restrict__ bits) {
  const int t = blockIdx.x * 256 + threadIdx.x;
  const unsigned long long ball = __ballot(mask[t] != 0);
  const int lane = threadIdx.x & 63;
  if ((lane & 31) == 0)
    bits[t >> 5] = (lane == 0) ? (unsigned)ball : (unsigned)(ball >> 32);
}

// ---------------------------------------------------------------------------
// fp32 -> bf16 convert, fused over q/k/v via blockIdx.y (8 elems/thread)
// ---------------------------------------------------------------------------
__global__ void cvt_f32_bf16_kernel(const float* __restrict__ q,
                                    const float* __restrict__ k,
                                    const float* __restrict__ v,
                                    unsigned short* __restrict__ qo,
                                    unsigned short* __restrict__ ko,
                                    unsigned short* __restrict__ vo, int n8) {
  int i = blockIdx.x * blockDim.x + threadIdx.x;
  if (i >= n8) return;
  const float* in = (blockIdx.y == 0) ? q : (blockIdx.y == 1) ? k : v;
  unsigned short* out = (blockIdx.y == 0) ? qo : (blockIdx.y == 1) ? ko : vo;
  const float4* p = reinterpret_cast<const float4*>(in) + (size_t)i * 2;
  float4 a = p[0], b = p[1];
  ushort4 o0 = {f2bf(a.x), f2bf(a.y), f2bf(a.z), f2bf(a.w)};
  ushort4 o1 = {f2bf(b.x), f2bf(b.y), f2bf(b.z), f2bf(b.w)};
  ushort4* o = reinterpret_cast<ushort4*>(out) + (size_t)i * 2;
  o[0] = o0;
  o[1] = o1;
}

// ---------------------------------------------------------------------------
// W [K=1024][N=1024] fp32 -> Wt bf16 [N][K], fused over 4 weights (blockIdx.z)
// ---------------------------------------------------------------------------
__global__ __launch_bounds__(256) void transpose_w_kernel(
    const float* __restrict__ w0, const float* __restrict__ w1,
    const float* __restrict__ w2, const float* __restrict__ w3,
    unsigned short* __restrict__ t0, unsigned short* __restrict__ t1,
    unsigned short* __restrict__ t2, unsigned short* __restrict__ t3) {
  __shared__ unsigned short tile[32][33];
  const int z = blockIdx.z;
  const float* W = (z == 0) ? w0 : (z == 1) ? w1 : (z == 2) ? w2 : w3;
  unsigned short* Wt = (z == 0) ? t0 : (z == 1) ? t1 : (z == 2) ? t2 : t3;
  const int r0 = blockIdx.y * 32, c0 = blockIdx.x * 32;
  const int t = threadIdx.x;
  {
    const int r = t >> 3, c4 = (t & 7) * 4;
    float4 v = *reinterpret_cast<const float4*>(&W[(size_t)(r0 + r) * D_ + c0 + c4]);
    tile[c4 + 0][r] = f2bf(v.x);
    tile[c4 + 1][r] = f2bf(v.y);
    tile[c4 + 2][r] = f2bf(v.z);
    tile[c4 + 3][r] = f2bf(v.w);
  }
  __syncthreads();
  {
    const int n = t >> 3, k4 = (t & 7) * 4;
    ushort4 o = {tile[n][k4 + 0], tile[n][k4 + 1], tile[n][k4 + 2], tile[n][k4 + 3]};
    *reinterpret_cast<ushort4*>(&Wt[(size_t)(c0 + n) * D_ + r0 + k4]) = o;
  }
}

// ---------------------------------------------------------------------------
// Q/K projections, 128x128 tile, BK=32, pure global_load_lds staging.
// z=0: Q -> bf16 [B,H,S,DK] scaled QSCALE; z=1: K -> [B,H,S,DK].
// ---------------------------------------------------------------------------
__global__ __launch_bounds__(256) void qkv_gemm_kernel(
    const unsigned short* __restrict__ qb, const unsigned short* __restrict__ kb,
    const unsigned short* __restrict__ wtq, const unsigned short* __restrict__ wtk,
    const float* __restrict__ bq, const float* __restrict__ bk,
    unsigned short* __restrict__ Qh, unsigned short* __restrict__ Kh) {
  constexpr int K = D_;
  __shared__ __attribute__((aligned(16))) unsigned short as_[128 * 32];
  __shared__ __attribute__((aligned(16))) unsigned short bs_[128 * 32];
  const int z = blockIdx.z;
  const unsigned short* A = (z == 0) ? qb : kb;
  const unsigned short* Wt = (z == 0) ? wtq : wtk;
  const float* bias = (z == 0) ? bq : bk;

  const int bm = blockIdx.x * 128, bn = blockIdx.y * 128;
  const int t = threadIdx.x, wv = t >> 6, lane = t & 63;
  const int r = lane & 15, g = lane >> 4;
  const int wr = (wv >> 1) * 64, wc = (wv & 1) * 64;
  const int srow = 16 * wv + (lane >> 2);
  const int scol = (lane & 3) * 8;

  f32x4 acc[4][4] = {};

  for (int k0 = 0; k0 < K; k0 += 32) {
    __syncthreads();
    __builtin_amdgcn_global_load_lds(
        (glb_u32*)&A[(size_t)(bm + srow) * K + k0 + scol],
        (lds_u32*)(as_ + wv * 512), 16, 0, 0);
    __builtin_amdgcn_global_load_lds(
        (glb_u32*)&A[(size_t)(bm + 64 + srow) * K + k0 + scol],
        (lds_u32*)(as_ + wv * 512 + 2048), 16, 0, 0);
    __builtin_amdgcn_global_load_lds(
        (glb_u32*)&Wt[(size_t)(bn + srow) * K + k0 + scol],
        (lds_u32*)(bs_ + wv * 512), 16, 0, 0);
    __builtin_amdgcn_global_load_lds(
        (glb_u32*)&Wt[(size_t)(bn + 64 + srow) * K + k0 + scol],
        (lds_u32*)(bs_ + wv * 512 + 2048), 16, 0, 0);
    __syncthreads();

    bf16x8 a[4], bfr[4];
#pragma unroll
    for (int mf = 0; mf < 4; ++mf)
      a[mf] = *reinterpret_cast<const bf16x8*>(&as_[(wr + 16 * mf + r) * 32 + 8 * g]);
#pragma unroll
    for (int nf = 0; nf < 4; ++nf)
      bfr[nf] = *reinterpret_cast<const bf16x8*>(&bs_[(wc + 16 * nf + r) * 32 + 8 * g]);
#pragma unroll
    for (int mf = 0; mf < 4; ++mf)
#pragma unroll
      for (int nf = 0; nf < 4; ++nf)
        acc[mf][nf] = __builtin_amdgcn_mfma_f32_16x16x32_bf16(a[mf], bfr[nf],
                                                              acc[mf][nf], 0, 0, 0);
  }

#pragma unroll
  for (int mf = 0; mf < 4; ++mf)
#pragma unroll
    for (int nf = 0; nf < 4; ++nf)
#pragma unroll
      for (int reg = 0; reg < 4; ++reg) {
        const int row = bm + wr + 16 * mf + 4 * g + reg;
        const int col = bn + wc + 16 * nf + r;
        const float v = acc[mf][nf][reg] + bias[col];
        const int bb = row >> 11, s = row & (S_ - 1);
        const int h = col >> 6, dk = col & (DK_ - 1);
        if (z == 0)
          Qh[(((size_t)(bb * H_ + h)) * S_ + s) * DK_ + dk] = f2bf(v * QSCALE);
        else
          Kh[(((size_t)(bb * H_ + h)) * S_ + s) * DK_ + dk] = f2bf(v);
      }
}

// ---------------------------------------------------------------------------
// V^T projection via swapped operands: C'[n=dk-row][m=s-row] = Wt·act^T.
// Rows (M'=1024) = Wt rows (h,dk); cols (N'=4096) = activation rows (b,s).
// Output write [dk][s] contiguous -> coalesced. bias indexed by ROW.
// Grid (8, 32).
// ---------------------------------------------------------------------------
__global__ __launch_bounds__(256) void vt_gemm_kernel(
    const unsigned short* __restrict__ Wt, const unsigned short* __restrict__ act,
    const float* __restrict__ bias, unsigned short* __restrict__ VT) {
  constexpr int K = D_;
  __shared__ __attribute__((aligned(16))) unsigned short as_[128 * 32];
  __shared__ __attribute__((aligned(16))) unsigned short bs_[128 * 32];
  const int bm = blockIdx.x * 128;  // over 1024 dk-rows
  const int bn = blockIdx.y * 128;  // over 4096 (b,s) rows
  const int t = threadIdx.x, wv = t >> 6, lane = t & 63;
  const int r = lane & 15, g = lane >> 4;
  const int wr = (wv >> 1) * 64, wc = (wv & 1) * 64;
  const int srow = 16 * wv + (lane >> 2);
  const int scol = (lane & 3) * 8;

  f32x4 acc[4][4] = {};

  for (int k0 = 0; k0 < K; k0 += 32) {
    __syncthreads();
    __builtin_amdgcn_global_load_lds(
        (glb_u32*)&Wt[(size_t)(bm + srow) * K + k0 + scol],
        (lds_u32*)(as_ + wv * 512), 16, 0, 0);
    __builtin_amdgcn_global_load_lds(
        (glb_u32*)&Wt[(size_t)(bm + 64 + srow) * K + k0 + scol],
        (lds_u32*)(as_ + wv * 512 + 2048), 16, 0, 0);
    __builtin_amdgcn_global_load_lds(
        (glb_u32*)&act[(size_t)(bn + srow) * K + k0 + scol],
        (lds_u32*)(bs_ + wv * 512), 16, 0, 0);
    __builtin_amdgcn_global_load_lds(
        (glb_u32*)&act[(size_t)(bn + 64 + srow) * K + k0 + scol],
        (lds_u32*)(bs_ + wv * 512 + 2048), 16, 0, 0);
    __syncthreads();

    bf16x8 a[4], bfr[4];
#pragma unroll
    for (int mf = 0; mf < 4; ++mf)
      a[mf] = *reinterpret_cast<const bf16x8*>(&as_[(wr + 16 * mf + r) * 32 + 8 * g]);
#pragma unroll
    for (int nf = 0; nf < 4; ++nf)
      bfr[nf] = *reinterpret_cast<const bf16x8*>(&bs_[(wc + 16 * nf + r) * 32 + 8 * g]);
#pragma unroll
    for (int mf = 0; mf < 4; ++mf)
#pragma unroll
      for (int nf = 0; nf < 4; ++nf)
        acc[mf][nf] = __builtin_amdgcn_mfma_f32_16x16x32_bf16(a[mf], bfr[nf],
                                                              acc[mf][nf], 0, 0, 0);
  }

#pragma unroll
  for (int mf = 0; mf < 4; ++mf)
#pragma unroll
    for (int nf = 0; nf < 4; ++nf)
#pragma unroll
      for (int reg = 0; reg < 4; ++reg) {
        const int row = bm + wr + 16 * mf + 4 * g + reg;  // h*64+dk
        const int col = bn + wc + 16 * nf + r;            // b*2048+s
        const float v = acc[mf][nf][reg] + bias[row];
        const int h = row >> 6, dk = row & (DK_ - 1);
        const int bb = col >> 11, s = col & (S_ - 1);
        VT[(((size_t)(bb * H_ + h)) * DK_ + dk) * S_ + s] = f2bf(v);
      }
}

// ---------------------------------------------------------------------------
// Output projection, 64x128 tile (grid 512 = 2 blocks/CU):
// ctx bf16 [B,S,D] @ Wo^T + bo -> fp32 out.
// ---------------------------------------------------------------------------
__global__ __launch_bounds__(256) void out_gemm_kernel(
    const unsigned short* __restrict__ A, const unsigned short* __restrict__ Wt,
    const float* __restrict__ bias, float* __restrict__ Cout) {
  constexpr int K = D_;
  __shared__ __attribute__((aligned(16))) unsigned short as_[64 * 32];
  __shared__ __attribute__((aligned(16))) unsigned short bs_[128 * 32];
  const int bm = blockIdx.x * 64, bn = blockIdx.y * 128;
  const int t = threadIdx.x, wv = t >> 6, lane = t & 63;
  const int r = lane & 15, g = lane >> 4;
  const int wr = (wv >> 1) * 32, wc = (wv & 1) * 64;
  const int srow = 16 * wv + (lane >> 2);
  const int scol = (lane & 3) * 8;

  f32x4 acc[2][4] = {};

  for (int k0 = 0; k0 < K; k0 += 32) {
    __syncthreads();
    __builtin_amdgcn_global_load_lds(
        (glb_u32*)&A[(size_t)(bm + srow) * K + k0 + scol],
        (lds_u32*)(as_ + wv * 512), 16, 0, 0);
    __builtin_amdgcn_global_load_lds(
        (glb_u32*)&Wt[(size_t)(bn + srow) * K + k0 + scol],
        (lds_u32*)(bs_ + wv * 512), 16, 0, 0);
    __builtin_amdgcn_global_load_lds(
        (glb_u32*)&Wt[(size_t)(bn + 64 + srow) * K + k0 + scol],
        (lds_u32*)(bs_ + wv * 512 + 2048), 16, 0, 0);
    __syncthreads();

    bf16x8 a[2], bfr[4];
#pragma unroll
    for (int mf = 0; mf < 2; ++mf)
      a[mf] = *reinterpret_cast<const bf16x8*>(&as_[(wr + 16 * mf + r) * 32 + 8 * g]);
#pragma unroll
    for (int nf = 0; nf < 4; ++nf)
      bfr[nf] = *reinterpret_cast<const bf16x8*>(&bs_[(wc + 16 * nf + r) * 32 + 8 * g]);
#pragma unroll
    for (int mf = 0; mf < 2; ++mf)
#pragma unroll
      for (int nf = 0; nf < 4; ++nf)
        acc[mf][nf] = __builtin_amdgcn_mfma_f32_16x16x32_bf16(a[mf], bfr[nf],
                                                              acc[mf][nf], 0, 0, 0);
  }

#pragma unroll
  for (int mf = 0; mf < 2; ++mf)
#pragma unroll
    for (int nf = 0; nf < 4; ++nf)
#pragma unroll
      for (int reg = 0; reg < 4; ++reg) {
        const int row = bm + wr + 16 * mf + 4 * g + reg;
        const int col = bn + wc + 16 * nf + r;
        Cout[(size_t)row * D_ + col] = acc[mf][nf][reg] + bias[col];
      }
}

// ---------------------------------------------------------------------------
// MFMA flash attention: 2 q-tiles per block (A then B, sharing K/V regs),
// 64-key iterations, v_exp_f32, swapped-QK^T 32x32x16, split-K(4), defer-max,
// T12 pack, T5 setprio. Grid 1024 x 256 thr.
// ---------------------------------------------------------------------------
__global__ __launch_bounds__(256, 2) void attn_mfma_kernel(
    const unsigned short* __restrict__ Qh, const unsigned short* __restrict__ Kh,
    const unsigned short* __restrict__ VT, const unsigned* __restrict__ mbits,
    unsigned short* __restrict__ ctx) {
  __shared__ float mlds[2][4][32];
  __shared__ float llds[2][4][32];
  __shared__ float olds[2][3][2][16][64];  // [tile][kh][dkblk][reg][lane]

  const int flat = blockIdx.x;
  const int bh = (flat & 7) * 4 + ((flat >> 3) & 3);  // 4 heads per XCD
  const int qblk = flat >> 5;                          // 0..31 (64 q-rows each)
  const int b = bh >> 4, h = bh & 15;
  const int kh = threadIdx.x >> 6, lane = threadIdx.x & 63;
  const int ql = lane & 31, hi = lane >> 5;
  const int qrowA = qblk * 64 + ql;
  const int qrowB = qrowA + 32;

  bf16x8 qfA[4], qfB[4];
  {
    const unsigned short* QrA = &Qh[((size_t)bh * S_ + qrowA) * DK_];
    const unsigned short* QrB = &Qh[((size_t)bh * S_ + qrowB) * DK_];
#pragma unroll
    for (int i = 0; i < 4; ++i) {
      qfA[i] = *(const bf16x8*)&QrA[16 * i + 8 * hi];
      qfB[i] = *(const bf16x8*)&QrB[16 * i + 8 * hi];
    }
  }

  const unsigned short* Khead = &Kh[(size_t)bh * S_ * DK_];
  const unsigned short* Vhead = &VT[(size_t)bh * DK_ * S_];

  f32x16 oA0 = {}, oA1 = {}, oB0 = {}, oB1 = {};
  float mA = NEG_BIG, lA = 0.f, mB = NEG_BIG, lB = 0.f;

  const unsigned short* kbase = Khead + ((size_t)(kh * 512 + ql)) * DK_ + 8 * hi;
  const unsigned short* vb0 = Vhead + (size_t)ql * S_ + kh * 512 + 8 * hi;
  const unsigned short* vb1 = vb0 + (size_t)32 * S_;
  const unsigned* mpA = &mbits[((size_t)b * S_ + qrowA) * (S_ / 32) + kh * 16];
  const unsigned* mpB = &mbits[((size_t)b * S_ + qrowB) * (S_ / 32) + kh * 16];

  bf16x8 kc0[4], kc1[4], vf0[4], vf1[4];
#pragma unroll
  for (int i = 0; i < 4; ++i) {
    kc0[i] = *(const bf16x8*)(kbase + 16 * i);
    kc1[i] = *(const bf16x8*)(kbase + 2048 + 16 * i);
  }
  kbase += 4096;

  // mask -> max -> defer-rescale -> exp -> sum -> pack -> PV for one q-tile
  auto process = [&](f32x16& s0, f32x16& s1, const uint2 mw, float& m, float& l,
                     f32x16& q0, f32x16& q1) {
    const unsigned w0m = mw.x >> (4 * hi), w1m = mw.y >> (4 * hi);
#pragma unroll
    for (int reg = 0; reg < 16; ++reg) {
      const int creg = (reg & 3) + 8 * (reg >> 2);
      if ((w0m >> creg) & 1u) s0[reg] = NEG_BIG;
      if ((w1m >> creg) & 1u) s1[reg] = NEG_BIG;
    }
    float px;
    {
      float t0 = fmaxf(fmaxf(s0[0], s0[1]), s0[2]);
      float t1 = fmaxf(fmaxf(s0[3], s0[4]), s0[5]);
      float t2 = fmaxf(fmaxf(s0[6], s0[7]), s0[8]);
      float t3 = fmaxf(fmaxf(s0[9], s0[10]), s0[11]);
      float t4 = fmaxf(fmaxf(s0[12], s0[13]), s0[14]);
      float t5 = fmaxf(fmaxf(s0[15], s1[0]), s1[1]);
      float t6 = fmaxf(fmaxf(s1[2], s1[3]), s1[4]);
      float t7 = fmaxf(fmaxf(s1[5], s1[6]), s1[7]);
      float t8 = fmaxf(fmaxf(s1[8], s1[9]), s1[10]);
      float t9 = fmaxf(fmaxf(s1[11], s1[12]), s1[13]);
      float ta = fmaxf(s1[14], s1[15]);
      float u0 = fmaxf(fmaxf(t0, t1), t2);
      float u1 = fmaxf(fmaxf(t3, t4), t5);
      float u2 = fmaxf(fmaxf(t6, t7), t8);
      float u3 = fmaxf(t9, ta);
      px = fmaxf(fmaxf(u0, u1), fmaxf(u2, u3));
    }
    px = fmaxf(px, __shfl_xor(px, 32));
    if (!__all(px - m <= 11.f)) {
      const float mn = fmaxf(m, px);
      const float al = vexp2(m - mn);
      m = mn;
      l *= al;
#pragma unroll
      for (int reg = 0; reg < 16; ++reg) { q0[reg] *= al; q1[reg] *= al; }
    }
#pragma unroll
    for (int reg = 0; reg < 16; ++reg) {
      s0[reg] = vexp2(s0[reg] - m);
      s1[reg] = vexp2(s1[reg] - m);
    }
    {
      float a0 = (s0[0] + s0[1]) + (s0[2] + s0[3]);
      float a1 = (s0[4] + s0[5]) + (s0[6] + s0[7]);
      float a2 = (s0[8] + s0[9]) + (s0[10] + s0[11]);
      float a3 = (s0[12] + s0[13]) + (s0[14] + s0[15]);
      float a4 = (s1[0] + s1[1]) + (s1[2] + s1[3]);
      float a5 = (s1[4] + s1[5]) + (s1[6] + s1[7]);
      float a6 = (s1[8] + s1[9]) + (s1[10] + s1[11]);
      float a7 = (s1[12] + s1[13]) + (s1[14] + s1[15]);
      float rs = ((a0 + a1) + (a2 + a3)) + ((a4 + a5) + (a6 + a7));
      rs += __shfl_xor(rs, 32);
      l += rs;
    }
    unsigned w0 = cvtpk(s0[0], s0[1]), w2p = cvtpk(s0[4], s0[5]);
    unsigned w1 = cvtpk(s0[2], s0[3]), w3p = cvtpk(s0[6], s0[7]);
    unsigned x0 = cvtpk(s0[8], s0[9]), x2p = cvtpk(s0[12], s0[13]);
    unsigned x1 = cvtpk(s0[10], s0[11]), x3p = cvtpk(s0[14], s0[15]);
    unsigned y0 = cvtpk(s1[0], s1[1]), y2p = cvtpk(s1[4], s1[5]);
    unsigned y1 = cvtpk(s1[2], s1[3]), y3p = cvtpk(s1[6], s1[7]);
    unsigned z0 = cvtpk(s1[8], s1[9]), z2p = cvtpk(s1[12], s1[13]);
    unsigned z1 = cvtpk(s1[10], s1[11]), z3p = cvtpk(s1[14], s1[15]);
    SWAP32(w0, w2p); SWAP32(w1, w3p); SWAP32(x0, x2p); SWAP32(x1, x3p);
    SWAP32(y0, y2p); SWAP32(y1, y3p); SWAP32(z0, z2p); SWAP32(z1, z3p);
    union { unsigned u[4]; bf16x8 v; } pu0, pu1, pu2, pu3;
    pu0.u[0] = w0; pu0.u[1] = w1; pu0.u[2] = w2p; pu0.u[3] = w3p;
    pu1.u[0] = x0; pu1.u[1] = x1; pu1.u[2] = x2p; pu1.u[3] = x3p;
    pu2.u[0] = y0; pu2.u[1] = y1; pu2.u[2] = y2p; pu2.u[3] = y3p;
    pu3.u[0] = z0; pu3.u[1] = z1; pu3.u[2] = z2p; pu3.u[3] = z3p;
    __builtin_amdgcn_s_setprio(1);
    q0 = __builtin_amdgcn_mfma_f32_32x32x16_bf16(pu0.v, vf0[0], q0, 0, 0, 0);
    q0 = __builtin_amdgcn_mfma_f32_32x32x16_bf16(pu1.v, vf0[1], q0, 0, 0, 0);
    q0 = __builtin_amdgcn_mfma_f32_32x32x16_bf16(pu2.v, vf0[2], q0, 0, 0, 0);
    q0 = __builtin_amdgcn_mfma_f32_32x32x16_bf16(pu3.v, vf0[3], q0, 0, 0, 0);
    q1 = __builtin_amdgcn_mfma_f32_32x32x16_bf16(pu0.v, vf1[0], q1, 0, 0, 0);
    q1 = __builtin_amdgcn_mfma_f32_32x32x16_bf16(pu1.v, vf1[1], q1, 0, 0, 0);
    q1 = __builtin_amdgcn_mfma_f32_32x32x16_bf16(pu2.v, vf1[2], q1, 0, 0, 0);
    q1 = __builtin_amdgcn_mfma_f32_32x32x16_bf16(pu3.v, vf1[3], q1, 0, 0, 0);
    __builtin_amdgcn_s_setprio(0);
  };

#pragma unroll 1
  for (int it = 0; it < 8; ++it) {
    const uint2 mwA = *reinterpret_cast<const uint2*>(mpA);
    const uint2 mwB = *reinterpret_cast<const uint2*>(mpB);
    mpA += 2;
    mpB += 2;
#pragma unroll
    for (int kk = 0; kk < 4; ++kk) {
      vf0[kk] = *(const bf16x8*)(vb0 + kk * 16);
      vf1[kk] = *(const bf16x8*)(vb1 + kk * 16);
    }
    vb0 += 64;
    vb1 += 64;

    // ---- QK^T tile A ----
    f32x16 sA0 = {}, sA1 = {};
    __builtin_amdgcn_s_setprio(1);
#pragma unroll
    for (int i = 0; i < 4; ++i)
      sA0 = __builtin_amdgcn_mfma_f32_32x32x16_bf16(kc0[i], qfA[i], sA0, 0, 0, 0);
#pragma unroll
    for (int i = 0; i < 4; ++i)
      sA1 = __builtin_amdgcn_mfma_f32_32x32x16_bf16(kc1[i], qfA[i], sA1, 0, 0, 0);
    __builtin_amdgcn_s_setprio(0);
    process(sA0, sA1, mwA, mA, lA, oA0, oA1);

    // ---- QK^T tile B (K regs still live) ----
    f32x16 sB0 = {}, sB1 = {};
    __builtin_amdgcn_s_setprio(1);
#pragma unroll
    for (int i = 0; i < 4; ++i)
      sB0 = __builtin_amdgcn_mfma_f32_32x32x16_bf16(kc0[i], qfB[i], sB0, 0, 0, 0);
#pragma unroll
    for (int i = 0; i < 4; ++i)
      sB1 = __builtin_amdgcn_mfma_f32_32x32x16_bf16(kc1[i], qfB[i], sB1, 0, 0, 0);
    __builtin_amdgcn_s_setprio(0);

    // ---- K reload for next iteration (covered by softmax+PV of tile B) ----
    if (it < 7) {
#pragma unroll
      for (int i = 0; i < 4; ++i) {
        kc0[i] = *(const bf16x8*)(kbase + 16 * i);
        kc1[i] = *(const bf16x8*)(kbase + 2048 + 16 * i);
      }
      kbase += 4096;
    }
    process(sB0, sB1, mwB, mB, lB, oB0, oB1);
  }

  // ---- 4-way split-K merge, both tiles ----
  if (lane < 32) {
    mlds[0][kh][ql] = mA;
    llds[0][kh][ql] = lA;
    mlds[1][kh][ql] = mB;
    llds[1][kh][ql] = lB;
  }
  if (kh < 3) {
#pragma unroll
    for (int reg = 0; reg < 16; ++reg) {
      olds[0][kh][0][reg][lane] = oA0[reg];
      olds[0][kh][1][reg][lane] = oA1[reg];
      olds[1][kh][0][reg][lane] = oB0[reg];
      olds[1][kh][1][reg][lane] = oB1[reg];
    }
  }
  __syncthreads();
  if (kh == 3) {
#pragma unroll
    for (int tile = 0; tile < 2; ++tile) {
      const f32x16& r0 = tile ? oB0 : oA0;
      const f32x16& r1 = tile ? oB1 : oA1;
#pragma unroll
      for (int reg = 0; reg < 16; ++reg) {
        const int crow = (reg & 3) + 8 * (reg >> 2) + 4 * hi;
        const float m0 = mlds[tile][0][crow], m1 = mlds[tile][1][crow];
        const float m2 = mlds[tile][2][crow], m3 = mlds[tile][3][crow];
        const float ms = fmaxf(fmaxf(m0, m1), fmaxf(m2, m3));
        const float f0 = vexp2(m0 - ms), f1 = vexp2(m1 - ms);
        const float f2 = vexp2(m2 - ms), f3 = vexp2(m3 - ms);
        const float ls = llds[tile][0][crow] * f0 + llds[tile][1][crow] * f1 +
                         llds[tile][2][crow] * f2 + llds[tile][3][crow] * f3;
        const float inv = (ms == NEG_BIG) ? 0.f : 1.f / ls;  // fully-masked -> 0
        const float v0 = (olds[tile][0][0][reg][lane] * f0 +
                          olds[tile][1][0][reg][lane] * f1 +
                          olds[tile][2][0][reg][lane] * f2 + r0[reg] * f3) * inv;
        const float v1 = (olds[tile][0][1][reg][lane] * f0 +
                          olds[tile][1][1][reg][lane] * f1 +
                          olds[tile][2][1][reg][lane] * f2 + r1[reg] * f3) * inv;
        const int q = qblk * 64 + tile * 32 + crow;
        unsigned short* cp = &ctx[((size_t)(b * S_ + q)) * D_ + h * DK_];
        cp[ql] = f2bf(v0);
        cp[32 + ql] = f2bf(v1);
      }
    }
  }
}

// ---------------------------------------------------------------------------
// Launch
// ---------------------------------------------------------------------------
extern "C" void kernel_launch(void* const* d_in, const int* in_sizes, int n_in,
                              void* d_out, int out_size, void* d_ws,
                              size_t ws_size, hipStream_t stream) {
  const float* query = (const float*)d_in[0];
  const float* key   = (const float*)d_in[1];
  const float* value = (const float*)d_in[2];
  const int*   mask  = (const int*)d_in[3];
  const float* Wq = (const float*)d_in[4];
  const float* bq = (const float*)d_in[5];
  const float* Wk = (const float*)d_in[6];
  const float* bk = (const float*)d_in[7];
  const float* Wv = (const float*)d_in[8];
  const float* bv = (const float*)d_in[9];
  const float* Wo = (const float*)d_in[10];
  const float* bo = (const float*)d_in[11];
  float* out = (float*)d_out;

  const size_t nElem = (size_t)B_ * S_ * D_;  // 4,194,304
  const size_t wElem = (size_t)D_ * D_;       // 1,048,576
  unsigned short* ws = (unsigned short*)d_ws;
  unsigned short* qb   = ws;
  unsigned short* kb   = qb + nElem;
  unsigned short* vb   = kb + nElem;
  unsigned short* wtq  = vb + nElem;
  unsigned short* wtk  = wtq + wElem;
  unsigned short* wtv  = wtk + wElem;
  unsigned short* wto  = wtv + wElem;
  unsigned short* Qh   = wto + wElem;
  unsigned short* Kh   = Qh + nElem;
  unsigned short* VT   = Kh + nElem;
  unsigned short* ctxb = VT + nElem;
  unsigned* mbits = (unsigned*)(ctxb + nElem);

  // 1) pack mask (ballot)
  pack_mask_kernel<<<(B_ * S_ * S_) / 256, 256, 0, stream>>>(mask, mbits);
  // 2) convert activations to bf16 (fused q/k/v)
  {
    const int n8 = (int)(nElem / 8);
    dim3 grid((n8 + 255) / 256, 3);
    cvt_f32_bf16_kernel<<<grid, 256, 0, stream>>>(query, key, value, qb, kb, vb, n8);
  }
  // 3) transpose+convert weights (fused x4)
  {
    dim3 grid(32, 32, 4);
    transpose_w_kernel<<<grid, 256, 0, stream>>>(Wq, Wk, Wv, Wo, wtq, wtk, wtv, wto);
  }
  // 4) Q/K projections
  {
    dim3 grid(32, 8, 2);
    qkv_gemm_kernel<<<grid, 256, 0, stream>>>(qb, kb, wtq, wtk, bq, bk, Qh, Kh);
  }
  // 5) V^T projection (swapped operands, coalesced [dk][s] writes)
  {
    dim3 grid(8, 32);
    vt_gemm_kernel<<<grid, 256, 0, stream>>>(wtv, vb, bv, VT);
  }
  // 6) attention (2 q-tiles/block, split-K x4)
  attn_mfma_kernel<<<1024, 256, 0, stream>>>(Qh, Kh, VT, mbits, ctxb);
  // 7) output projection (64x128 tiles, 512 blocks)
  {
    dim3 grid(64, 8);
    out_gemm_kernel<<<grid, 256, 0, stream>>>(ctxb, wto, bo, out);
  }
}